// Round 7
// baseline (472.770 us; speedup 1.0000x reference)
//
#include <hip/hip_runtime.h>
#include <cstdint>

// Problem constants (B, BS, M, D) = (64, 8, 512, 256), neg = B/BS = 8
#define NEG_FILL_F (-10000000000.0f)
constexpr int BB     = 64;
constexpr int BS_    = 8;
constexpr int MM     = 512;
constexpr int DD     = 256;
constexpr int ROWS_X = BB * MM;           // 32768
constexpr int ROWS_Y = BS_ * MM;          // 4096
constexpr int ROWS_ALL = ROWS_X + ROWS_Y; // 36864
// Triple-split k' = 768 slots, planar pairing:
//   slots [0,256):   A=h, B=h
//   slots [256,512): A=l, B=h
//   slots [512,768): A=h, B=l
// Storage is 512 shorts/row: [h-plane | l-plane]; h-plane is read twice.
// K-loops run 32-slot windows; window w (0..23) lives in exactly one plane.
constexpr int KS     = 512;               // stored row length (shorts)

typedef __attribute__((ext_vector_type(8))) short short8;   // 8 bf16 = 4 VGPRs
typedef __attribute__((ext_vector_type(4))) float f32x4;    // MFMA C/D

__device__ inline unsigned short rne_bf16(float f) {
    unsigned int u = __float_as_uint(f);
    u = (u + 0x7FFFu + ((u >> 16) & 1u)) >> 16;
    return (unsigned short)u;
}
__device__ inline float bf2f(unsigned short h) {
    return __uint_as_float(((unsigned int)h) << 16);
}

__device__ inline f32x4 mfma16(short8 a, short8 b, f32x4 c) {
    return __builtin_amdgcn_mfma_f32_16x16x32_bf16(a, b, c, 0, 0, 0);
}

// Async global->LDS 16B copy. LDS dst MUST be wave-uniform; HW adds lane*16.
__device__ inline void gld16(const unsigned short* g, unsigned short* l) {
    __builtin_amdgcn_global_load_lds(
        (const __attribute__((address_space(1))) unsigned int*)g,
        (__attribute__((address_space(3))) unsigned int*)l, 16, 0, 0);
}

// Window -> column base within the planar [h|l] row (shorts), 32-slot windows.
// A pairing (h,l,h): plane 1 is the l-plane. B pairing (h,h,l): plane 2 is l.
__device__ inline int awin32(int w) { return (((w >> 3) == 1) ? 256 : 0) + (w & 7) * 32; }
__device__ inline int bwin32(int w) { return (((w >> 3) == 2) ? 256 : 0) + (w & 7) * 32; }

// Stage one [128][32] bf16 tile (8 KB), XOR-swizzled (chunk ^= row&3), async.
// (256-thread version used by proj.) LDS dst wave-uniform, src per-lane.
__device__ inline void stage32(unsigned short* dstbase,
                               const unsigned short* __restrict__ src,
                               int srccol, int wave, int lane)
{
    #pragma unroll
    for (int s4 = 0; s4 < 2; ++s4) {
        const int c   = s4 * 256 + wave * 64 + lane;  // 0..511
        const int r   = c >> 2;
        const int cin = (c & 3) ^ (r & 3);
        gld16(src + (size_t)r * KS + srccol + cin * 8,
              dstbase + (size_t)(s4 * 256 + wave * 64) * 8);
    }
}

// 4 fragments, rows rbase+{0,16,32,48}+lid, global chunk = quad, from a
// [*][32] XOR tile (any row count).
__device__ inline void frag4_x32(const unsigned short (*T)[32], int rbase,
                                 int lid, int quad, short8 f[4])
{
    const int q = quad ^ (lid & 3);
    #pragma unroll
    for (int i = 0; i < 4; ++i)
        f[i] = *(const short8*)&T[rbase + i * 16 + lid][q * 8];
}

// ---------------------------------------------------------------------------
// W -> Wb: [3][256][512] planar (h-plane | l-plane). 96 blocks x 256.
// ---------------------------------------------------------------------------
__global__ __launch_bounds__(256) void convw_kernel(
    const float* __restrict__ Wq, const float* __restrict__ Wk,
    const float* __restrict__ Wv, unsigned short* __restrict__ Wb)
{
    const int g  = blockIdx.x * 256 + threadIdx.x;   // < 24576
    const int e  = g * 8;                            // over 3*65536
    const int zi = e >> 16;
    const int off = e & 65535;
    const int row = off >> 8, k0 = off & 255;
    const float* W = (zi == 0) ? Wq : (zi == 1 ? Wk : Wv);
    float4 v0 = *(const float4*)(W + off);
    float4 v1 = *(const float4*)(W + off + 4);
    const float fv[8] = {v0.x, v0.y, v0.z, v0.w, v1.x, v1.y, v1.z, v1.w};
    short8 hh, ll;
    #pragma unroll
    for (int i = 0; i < 8; ++i) {
        unsigned short h = rne_bf16(fv[i]);
        hh[i] = (short)h;
        ll[i] = (short)rne_bf16(fv[i] - bf2f(h));
    }
    unsigned short* dst = Wb + (size_t)zi * 131072 + (size_t)row * KS;
    *(short8*)(dst + k0)       = hh;
    *(short8*)(dst + 256 + k0) = ll;
}

// ---------------------------------------------------------------------------
// x|y -> xs: [36864][512] planar (h | l). grid = 4608 x 256.
// ---------------------------------------------------------------------------
__global__ __launch_bounds__(256) void convx_kernel(
    const float* __restrict__ x, const float* __restrict__ y,
    unsigned short* __restrict__ xs)
{
    const int g   = blockIdx.x * 256 + threadIdx.x;  // < 1179648
    const int row = g >> 5;
    const int off = (g & 31) * 8;
    const float* src = (row < ROWS_X) ? (x + (size_t)row * DD)
                                      : (y + (size_t)(row - ROWS_X) * DD);
    float4 v0 = *(const float4*)(src + off);
    float4 v1 = *(const float4*)(src + off + 4);
    const float fv[8] = {v0.x, v0.y, v0.z, v0.w, v1.x, v1.y, v1.z, v1.w};
    short8 hh, ll;
    #pragma unroll
    for (int i = 0; i < 8; ++i) {
        unsigned short h = rne_bf16(fv[i]);
        hh[i] = (short)h;
        ll[i] = (short)rne_bf16(fv[i] - bf2f(h));
    }
    unsigned short* dst = xs + (size_t)row * KS;
    *(short8*)(dst + off)       = hh;
    *(short8*)(dst + 256 + off) = ll;
}

// ---------------------------------------------------------------------------
// Projections via MFMA (k'=768 planar, 24 x 32-slot windows, double-buffered
// 2-phase prefetch). XCD-chunked: 6 consumers of each A-panel on one XCD.
// z=0 -> Qa, z=1 -> Kb (planar [h|l]); z=2 -> Vt[b][d][j]. grid = 1728.
// ---------------------------------------------------------------------------
__global__ __launch_bounds__(256) void proj_kernel(
    const unsigned short* __restrict__ xs,
    const unsigned short* __restrict__ Wb,
    unsigned short* __restrict__ Qa, unsigned short* __restrict__ Kb,
    unsigned short* __restrict__ Vt)
{
    // 1728 = 8 XCD * 216; per XCD: 36 consecutive bx, each with 6 (by,bz)
    const int xcd = blockIdx.x & 7, idx = blockIdx.x >> 3;
    const int lin = xcd * 216 + idx;
    const int bx  = lin / 6;
    const int rem = lin - bx * 6;
    const int z    = rem >> 1;
    const int row0 = bx * 128;
    const int col0 = (rem & 1) * 128;
    const unsigned short* Asrc = xs + (size_t)row0 * KS;
    const unsigned short* Bsrc = Wb + (size_t)z * 131072 + (size_t)col0 * KS;

    __shared__ unsigned short Ab[2][128][32];
    __shared__ unsigned short Bb[2][128][32];

    const int t = threadIdx.x;
    const int wave = t >> 6, lane = t & 63, quad = lane >> 4, lid = lane & 15;
    const int wrow = (wave & 1) * 64, wcol = (wave >> 1) * 64;

    f32x4 acc[4][4];
    #pragma unroll
    for (int i = 0; i < 4; ++i)
        #pragma unroll
        for (int j = 0; j < 4; ++j) acc[i][j] = (f32x4){0.f, 0.f, 0.f, 0.f};

    stage32(&Ab[0][0][0], Asrc, awin32(0), wave, lane);
    stage32(&Bb[0][0][0], Bsrc, bwin32(0), wave, lane);
    __syncthreads();
    int cur = 0;
    for (int w = 0; w < 23; ++w) {
        stage32(&Ab[cur ^ 1][0][0], Asrc, awin32(w + 1), wave, lane);
        stage32(&Bb[cur ^ 1][0][0], Bsrc, bwin32(w + 1), wave, lane);
        short8 af[4], bf_[4];
        frag4_x32(Ab[cur], wrow, lid, quad, af);
        frag4_x32(Bb[cur], wcol, lid, quad, bf_);
        #pragma unroll
        for (int i = 0; i < 4; ++i)
            #pragma unroll
            for (int j = 0; j < 4; ++j)
                acc[i][j] = mfma16(af[i], bf_[j], acc[i][j]);
        __syncthreads();
        cur ^= 1;
    }
    {
        short8 af[4], bf_[4];
        frag4_x32(Ab[cur], wrow, lid, quad, af);
        frag4_x32(Bb[cur], wcol, lid, quad, bf_);
        #pragma unroll
        for (int i = 0; i < 4; ++i)
            #pragma unroll
            for (int j = 0; j < 4; ++j)
                acc[i][j] = mfma16(af[i], bf_[j], acc[i][j]);
    }

    if (z == 2) {
        #pragma unroll
        for (int i = 0; i < 4; ++i) {
            const int rg = row0 + wrow + i * 16 + quad * 4;
            const int b  = rg >> 9;
            const int j  = rg & 511;
            #pragma unroll
            for (int jt = 0; jt < 4; ++jt) {
                const int col = col0 + wcol + jt * 16 + lid;
                *(ushort4*)(Vt + (size_t)b * DD * MM + (size_t)col * MM + j) =
                    make_ushort4(rne_bf16(acc[i][jt][0]), rne_bf16(acc[i][jt][1]),
                                 rne_bf16(acc[i][jt][2]), rne_bf16(acc[i][jt][3]));
            }
        }
    } else {
        unsigned short* dst = (z == 0) ? Qa : Kb;
        #pragma unroll
        for (int i = 0; i < 4; ++i) {
            const int rg = row0 + wrow + i * 16 + quad * 4;
            #pragma unroll
            for (int r = 0; r < 4; ++r) {
                unsigned short* rowp = dst + (size_t)(rg + r) * KS;
                #pragma unroll
                for (int jt = 0; jt < 4; ++jt) {
                    const int col = col0 + wcol + jt * 16 + lid;
                    const float v = acc[i][jt][r];
                    unsigned short h = rne_bf16(v);
                    rowp[col]       = h;                          // h-plane
                    rowp[256 + col] = rne_bf16(v - bf2f(h));      // l-plane
                }
            }
        }
    }
}

// ---------------------------------------------------------------------------
// FUSED self attention (x z<64, y z>=64): QK^T (k'=768 planar, 24 windows,
// dbuf) -> masked S write + full-row softmax stats -> P=exp(S-m) into LDS
// (bf16 [64][520], pad 8 -> per-phase conflict-free b128 reads) -> PV GEMM
// (Vt async XOR tiles, 16 windows dbuf) -> O = PV * (1/sum).
// Eliminates the P global round-trip (75 MB) and the separate ctx kernel.
// grid = 576 (8 XCD x 9 z x 8 row-blocks), 512 threads (8 waves).
// LDS ~101.5 KB -> 1 block/CU. Numerics bit-identical to the split version.
// ---------------------------------------------------------------------------
__global__ __launch_bounds__(512) void self_attn_kernel(
    const unsigned short* __restrict__ Qa,
    const unsigned short* __restrict__ Kb,
    const int* __restrict__ mask_x, const int* __restrict__ mask_y,
    const unsigned short* __restrict__ Vt_base,
    float* __restrict__ Sbase, float* __restrict__ Obase)
{
    const int xcd = blockIdx.x & 7, idx = blockIdx.x >> 3;
    const int lin = xcd * 72 + idx;          // 576 = 8*72
    const int z    = lin >> 3;               // 0..71
    const int brow = (lin & 7) * 64;
    const unsigned short* Asrc = Qa + (size_t)(z * MM + brow) * KS;
    const unsigned short* Bsrc = Kb + (size_t)z * MM * KS;
    const unsigned short* Vt   = Vt_base + (size_t)z * DD * MM;
    const int* msk = (z < 64) ? (mask_x + z * MM) : (mask_y + (z - 64) * MM);
    float* S = Sbase + (size_t)z * MM * MM;
    float* O = Obase + (size_t)z * MM * DD;

    __shared__ union {
        struct { unsigned short A[2][64][32];          // 8 KB
                 unsigned short B[2][512][32]; } qk;   // 64 KB
        struct { unsigned short P[64][520];            // 66.6 KB (pad 8)
                 unsigned short V[2][256][32]; } pv;   // 32 KB
    } sh;
    __shared__ float pm8[64][8], ps8[64][8], smx[64], sin_[64];

    const int t = threadIdx.x;               // 0..511
    const int wave = t >> 6, lane = t & 63, quad = lane >> 4, lid = lane & 15;
    const int wcol = wave * 64;              // QK col strip per wave

    f32x4 acc[4][4];
    #pragma unroll
    for (int i = 0; i < 4; ++i)
        #pragma unroll
        for (int j = 0; j < 4; ++j) acc[i][j] = (f32x4){0.f, 0.f, 0.f, 0.f};

    // ---- QK phase -------------------------------------------------------
    auto stageQK = [&](int buf, int w) {
        if (wave < 4) {                      // A: 256 chunks (wave-uniform br)
            const int c = t;                 // 0..255
            const int r = c >> 2, cin = (c & 3) ^ (r & 3);
            gld16(Asrc + (size_t)r * KS + awin32(w) + cin * 8,
                  &sh.qk.A[buf][0][0] + (size_t)(wave * 64) * 8);
        }
        const int bw = bwin32(w);
        #pragma unroll
        for (int k = 0; k < 4; ++k) {        // B: 2048 chunks
            const int c = k * 512 + t;
            const int r = c >> 2, cin = (c & 3) ^ (r & 3);
            gld16(Bsrc + (size_t)r * KS + bw + cin * 8,
                  &sh.qk.B[buf][0][0] + (size_t)(k * 512 + wave * 64) * 8);
        }
    };
    auto compQK = [&](int buf) {
        short8 af[4], bf_[4];
        frag4_x32(sh.qk.A[buf], 0, lid, quad, af);
        frag4_x32(sh.qk.B[buf], wcol, lid, quad, bf_);
        #pragma unroll
        for (int i = 0; i < 4; ++i)
            #pragma unroll
            for (int j = 0; j < 4; ++j)
                acc[i][j] = mfma16(af[i], bf_[j], acc[i][j]);
    };

    stageQK(0, 0);
    __syncthreads();
    int cur = 0;
    for (int w = 0; w < 23; ++w) {
        stageQK(cur ^ 1, w + 1);
        compQK(cur);
        __syncthreads();
        cur ^= 1;
    }
    compQK(cur);

    // ---- epilogue 1: masked S write + per-wave row partials -------------
    int mcol[4];
    #pragma unroll
    for (int j = 0; j < 4; ++j) mcol[j] = msk[wcol + j * 16 + lid];

    #pragma unroll
    for (int i = 0; i < 4; ++i) {
        #pragma unroll
        for (int r = 0; r < 4; ++r) {
            const int rl = i * 16 + quad * 4 + r;
            const bool mr = (msk[brow + rl] != 0);
            float* Srow = S + (size_t)(brow + rl) * MM;
            float vv[4];
            float mt = -3.4e38f;
            #pragma unroll
            for (int j = 0; j < 4; ++j) {
                const int col = wcol + j * 16 + lid;
                const bool valid = mr && (mcol[j] != 0);
                vv[j] = valid ? acc[i][j][r] : NEG_FILL_F;
                Srow[col] = vv[j];
                mt = fmaxf(mt, vv[j]);
            }
            #pragma unroll
            for (int o = 1; o < 16; o <<= 1) mt = fmaxf(mt, __shfl_xor(mt, o));
            float se = 0.f;
            #pragma unroll
            for (int j = 0; j < 4; ++j) se += __expf(vv[j] - mt);
            #pragma unroll
            for (int o = 1; o < 16; o <<= 1) se += __shfl_xor(se, o);
            if (lid == 0) { pm8[rl][wave] = mt; ps8[rl][wave] = se; }
        }
    }
    __syncthreads();
    if (t < 64) {
        float m = -3.4e38f;
        #pragma unroll
        for (int c = 0; c < 8; ++c) m = fmaxf(m, pm8[t][c]);
        float s = 0.f;
        #pragma unroll
        for (int c = 0; c < 8; ++c) s += ps8[t][c] * __expf(pm8[t][c] - m);
        smx[t] = m;
        sin_[t] = 1.0f / s;                  // all-masked: m=NEG, s=512
    }
    __syncthreads();

    // ---- P -> LDS (overlaps retired qk region) + first V window ---------
    auto stageV = [&](int buf, int w) {
        #pragma unroll
        for (int k = 0; k < 2; ++k) {        // 1024 chunks
            const int c = k * 512 + t;
            const int r = c >> 2, cin = (c & 3) ^ (r & 3);
            gld16(Vt + (size_t)r * MM + w * 32 + cin * 8,
                  &sh.pv.V[buf][0][0] + (size_t)(k * 512 + wave * 64) * 8);
        }
    };
    stageV(0, 0);
    #pragma unroll
    for (int i = 0; i < 4; ++i) {
        #pragma unroll
        for (int r = 0; r < 4; ++r) {
            const int rl = i * 16 + quad * 4 + r;
            const bool mr = (msk[brow + rl] != 0);
            const float m = smx[rl];
            #pragma unroll
            for (int j = 0; j < 4; ++j) {
                const int col = wcol + j * 16 + lid;
                const bool valid = mr && (mcol[j] != 0);
                const float v = valid ? acc[i][j][r] : NEG_FILL_F;
                sh.pv.P[rl][col] = rne_bf16(__expf(v - m));
            }
        }
    }
    __syncthreads();

    // ---- PV phase: O[64][256] over K=512, 16 windows dbuf ---------------
    f32x4 acc2[4][2];
    #pragma unroll
    for (int i = 0; i < 4; ++i)
        #pragma unroll
        for (int j = 0; j < 2; ++j) acc2[i][j] = (f32x4){0.f, 0.f, 0.f, 0.f};
    const int pcol = wave * 32;              // PV col strip per wave

    auto compPV = [&](int buf, int w) {
        short8 af[4], bf_[2];
        #pragma unroll
        for (int i = 0; i < 4; ++i)
            af[i] = *(const short8*)&sh.pv.P[i * 16 + lid][w * 32 + quad * 8];
        const int q = quad ^ (lid & 3);
        #pragma unroll
        for (int j = 0; j < 2; ++j)
            bf_[j] = *(const short8*)&sh.pv.V[buf][pcol + j * 16 + lid][q * 8];
        #pragma unroll
        for (int i = 0; i < 4; ++i)
            #pragma unroll
            for (int j = 0; j < 2; ++j)
                acc2[i][j] = mfma16(af[i], bf_[j], acc2[i][j]);
    };

    int cv = 0;
    for (int w = 0; w < 15; ++w) {
        stageV(cv ^ 1, w + 1);
        compPV(cv, w);
        __syncthreads();
        cv ^= 1;
    }
    compPV(cv, 15);

    #pragma unroll
    for (int i = 0; i < 4; ++i) {
        const int rl0 = i * 16 + quad * 4;
        float inv[4];
        #pragma unroll
        for (int r = 0; r < 4; ++r) inv[r] = sin_[rl0 + r];
        #pragma unroll
        for (int j = 0; j < 2; ++j) {
            const int col = pcol + j * 16 + lid;
            #pragma unroll
            for (int r = 0; r < 4; ++r)
                O[(size_t)(brow + rl0 + r) * DD + col] = acc2[i][j][r] * inv[r];
        }
    }
}

// ---------------------------------------------------------------------------
// FUSED cross scores (xy): 64 rows x full 512 cols, single bf16 K=256
// (h-plane), 8 windows dbuf. Writes FINAL probs (softmax fused, no raw S
// round-trip) + mask floats. grid = 512 (8 XCD x 8 zz s-major x 8 rb).
// ---------------------------------------------------------------------------
__global__ __launch_bounds__(256, 2) void scores_xy_kernel(
    const unsigned short* __restrict__ Qa, const unsigned short* __restrict__ Kb,
    const int* __restrict__ mask_x, const int* __restrict__ mask_y,
    float* __restrict__ Prb, float* __restrict__ Mb)
{
    const int xcd = blockIdx.x & 7, idx = blockIdx.x >> 3;
    const int lin = xcd * 64 + idx;          // 512 = 8*64
    const int zz = lin >> 3;                 // s-major
    const int brow = (lin & 7) * 64;
    const int s = zz >> 3, n = zz & 7;
    const int zo = n * 8 + s;                // output slot (reference order)
    const int bq = s * 8 + n;                // x batch
    const int bk = s;                        // y batch
    const unsigned short* Asrc = Qa + (size_t)(bq * MM + brow) * KS;
    const unsigned short* Bsrc = Kb + (size_t)(ROWS_X + bk * MM) * KS;
    const int* mq = mask_x + bq * MM;
    const int* mk = mask_y + bk * MM;
    float* Pl = Prb + (size_t)zo * MM * MM;
    float* Ml = Mb  + (size_t)zo * MM * MM;

    __shared__ unsigned short Ab[2][64][32];
    __shared__ unsigned short Bb[2][512][32];
    __shared__ float pm4[64][4], ps4[64][4], smx[64], sin_[64];

    const int t = threadIdx.x;
    const int wave = t >> 6, lane = t & 63, quad = lane >> 4, lid = lane & 15;
    const int wcol = wave * 128;

    f32x4 acc[4][8];
    #pragma unroll
    for (int i = 0; i < 4; ++i)
        #pragma unroll
        for (int j = 0; j < 8; ++j) acc[i][j] = (f32x4){0.f, 0.f, 0.f, 0.f};

    auto stage = [&](int buf, int w) {
        {
            const int r = t >> 2, cin = (t & 3) ^ (r & 3);
            gld16(Asrc + (size_t)r * KS + w * 32 + cin * 8,
                  &Ab[buf][0][0] + (size_t)(wave * 64) * 8);
        }
        #pragma unroll
        for (int k = 0; k < 8; ++k) {
            const int c = k * 256 + t;
            const int r = c >> 2, cin = (c & 3) ^ (r & 3);
            gld16(Bsrc + (size_t)r * KS + w * 32 + cin * 8,
                  &Bb[buf][0][0] + (size_t)(k * 256 + wave * 64) * 8);
        }
    };
    auto comp = [&](int buf) {
        short8 af[4], bv[8];
        frag4_x32(Ab[buf], 0, lid, quad, af);
        frag4_x32(Bb[buf], wcol, lid, quad, bv);
        frag4_x32(Bb[buf], wcol + 64, lid, quad, bv + 4);
        #pragma unroll
        for (int i = 0; i < 4; ++i)
            #pragma unroll
            for (int j = 0; j < 8; ++j)
                acc[i][j] = mfma16(af[i], bv[j], acc[i][j]);
    };

    stage(0, 0);
    __syncthreads();
    int cur = 0;
    for (int w = 0; w < 7; ++w) {
        stage(cur ^ 1, w + 1);
        comp(cur);
        __syncthreads();
        cur ^= 1;
    }
    comp(cur);

    int mcol[8];
    #pragma unroll
    for (int j = 0; j < 8; ++j) mcol[j] = mk[wcol + j * 16 + lid];

    // pass 1: mask floats + partials
    #pragma unroll
    for (int i = 0; i < 4; ++i) {
        #pragma unroll
        for (int r = 0; r < 4; ++r) {
            const int rl = i * 16 + quad * 4 + r;
            const bool mr = (mq[brow + rl] != 0);
            float* Mrow = Ml + (size_t)(brow + rl) * MM;
            float vv[8];
            float mt = -3.4e38f;
            #pragma unroll
            for (int j = 0; j < 8; ++j) {
                const int col = wcol + j * 16 + lid;
                const bool valid = mr && (mcol[j] != 0);
                vv[j] = valid ? acc[i][j][r] : NEG_FILL_F;
                Mrow[col] = valid ? 1.0f : 0.0f;
                mt = fmaxf(mt, vv[j]);
            }
            #pragma unroll
            for (int o = 1; o < 16; o <<= 1) mt = fmaxf(mt, __shfl_xor(mt, o));
            float se = 0.f;
            #pragma unroll
            for (int j = 0; j < 8; ++j) se += __expf(vv[j] - mt);
            #pragma unroll
            for (int o = 1; o < 16; o <<= 1) se += __shfl_xor(se, o);
            if (lid == 0) { pm4[rl][wave] = mt; ps4[rl][wave] = se; }
        }
    }
    __syncthreads();
    if (t < 64) {
        const float m = fmaxf(fmaxf(pm4[t][0], pm4[t][1]),
                              fmaxf(pm4[t][2], pm4[t][3]));
        float ssum = 0.f;
        #pragma unroll
        for (int c = 0; c < 4; ++c) ssum += ps4[t][c] * __expf(pm4[t][c] - m);
        smx[t] = m;
        sin_[t] = 1.0f / ssum;
    }
    __syncthreads();
    // pass 2: final probs (no raw-S write, no second kernel)
    #pragma unroll
    for (int i = 0; i < 4; ++i) {
        #pragma unroll
        for (int r = 0; r < 4; ++r) {
            const int rl = i * 16 + quad * 4 + r;
            const bool mr = (mq[brow + rl] != 0);
            const float m = smx[rl], iv = sin_[rl];
            float* Prow = Pl + (size_t)(brow + rl) * MM;
            #pragma unroll
            for (int j = 0; j < 8; ++j) {
                const int col = wcol + j * 16 + lid;
                const bool valid = mr && (mcol[j] != 0);
                const float v = valid ? acc[i][j][r] : NEG_FILL_F;
                Prow[col] = __expf(v - m) * iv;
            }
        }
    }
}

// ---------------------------------------------------------------------------
// y_len: one block per s, 64-lane reduce of mask_y[s,:]; lane n<8 writes n*8+s.
// ---------------------------------------------------------------------------
__global__ void ylen_kernel(const int* __restrict__ mask_y, float* __restrict__ out)
{
    const int s = blockIdx.x;
    const int lane = threadIdx.x;
    int c = 0;
    #pragma unroll
    for (int k = 0; k < 8; ++k) c += (mask_y[s * MM + k * 64 + lane] != 0);
    #pragma unroll
    for (int off = 32; off; off >>= 1) c += __shfl_xor(c, off);
    if (lane < 8) out[lane * 8 + s] = (float)c;
}

// ---------------------------------------------------------------------------
extern "C" void kernel_launch(void* const* d_in, const int* in_sizes, int n_in,
                              void* d_out, int out_size, void* d_ws, size_t ws_size,
                              hipStream_t stream)
{
    const float* x      = (const float*)d_in[0];
    const float* y      = (const float*)d_in[1];
    const int*   mask_x = (const int*)d_in[2];
    const int*   mask_y = (const int*)d_in[3];
    const float* Wq     = (const float*)d_in[4];
    const float* Wk     = (const float*)d_in[5];
    const float* Wv     = (const float*)d_in[6];
    float* out = (float*)d_out;

    // Workspace: Wb | xs | Qa | Kb | Vt
    unsigned short* Wb = (unsigned short*)d_ws;            // 3*256*512   = 393216
    unsigned short* xs = Wb + 393216;                      // 36864*512   = 18874368
    unsigned short* Qa = xs + 18874368;
    unsigned short* Kb = Qa + 18874368;
    unsigned short* Vt = Kb + 18874368;                    // 72*256*512  = 9437184

    // Output slots (floats, concatenated in reference return order)
    float* out_ctx   = out;                 // 64*512*256 + 8*512*256
    float* out_sx    = out + 9437184;       // 64*512*512 (+sy)
    float* out_pxy   = out + 28311552;      // 8*8*512*512
    float* out_mxy   = out + 45088768;      // 8*8*512*512
    float* out_ylen  = out + 61865984;      // 8*8

    // 1. splits + y_len
    convw_kernel<<<96, 256, 0, stream>>>(Wq, Wk, Wv, Wb);
    convx_kernel<<<4608, 256, 0, stream>>>(x, y, xs);
    ylen_kernel<<<8, 64, 0, stream>>>(mask_y, out_ylen);

    // 2. Projections
    proj_kernel<<<1728, 256, 0, stream>>>(xs, Wb, Qa, Kb, Vt);

    // 3. Fused self attention: S + softmax + PV -> O (no P round-trip)
    self_attn_kernel<<<576, 512, 0, stream>>>(
        Qa, Kb, mask_x, mask_y, Vt, out_sx, out_ctx);

    // 4. Cross scores (fused softmax -> final probs + mask)
    scores_xy_kernel<<<512, 256, 0, stream>>>(
        Qa, Kb, mask_x, mask_y, out_pxy, out_mxy);
}

// Round 8
// 462.478 us; speedup vs baseline: 1.0223x; 1.0223x over previous
//
#include <hip/hip_runtime.h>
#include <cstdint>

// Problem constants (B, BS, M, D) = (64, 8, 512, 256), neg = B/BS = 8
#define NEG_FILL_F (-10000000000.0f)
constexpr int BB     = 64;
constexpr int BS_    = 8;
constexpr int MM     = 512;
constexpr int DD     = 256;
constexpr int ROWS_X = BB * MM;           // 32768
constexpr int ROWS_Y = BS_ * MM;          // 4096
constexpr int ROWS_ALL = ROWS_X + ROWS_Y; // 36864
// Triple-split k' = 768 slots, planar pairing:
//   slots [0,256):   A=h, B=h
//   slots [256,512): A=l, B=h
//   slots [512,768): A=h, B=l
// Storage is 512 shorts/row: [h-plane | l-plane]; h-plane is read twice.
constexpr int KS     = 512;               // stored row length (shorts)

typedef __attribute__((ext_vector_type(8))) short short8;   // 8 bf16 = 4 VGPRs
typedef __attribute__((ext_vector_type(4))) float f32x4;    // MFMA C/D

__device__ inline unsigned short rne_bf16(float f) {
    unsigned int u = __float_as_uint(f);
    u = (u + 0x7FFFu + ((u >> 16) & 1u)) >> 16;
    return (unsigned short)u;
}
__device__ inline float bf2f(unsigned short h) {
    return __uint_as_float(((unsigned int)h) << 16);
}

__device__ inline f32x4 mfma16(short8 a, short8 b, f32x4 c) {
    return __builtin_amdgcn_mfma_f32_16x16x32_bf16(a, b, c, 0, 0, 0);
}

// Async global->LDS 16B copy. LDS dst MUST be wave-uniform; HW adds lane*16.
__device__ inline void gld16(const unsigned short* g, unsigned short* l) {
    __builtin_amdgcn_global_load_lds(
        (const __attribute__((address_space(1))) unsigned int*)g,
        (__attribute__((address_space(3))) unsigned int*)l, 16, 0, 0);
}

// 64-slot windows over k'=768 (12 windows). Window w lives in one plane.
__device__ inline int awin64(int w) { return (((w >> 2) == 1) ? 256 : 0) + (w & 3) * 64; }
__device__ inline int bwin64(int w) { return (((w >> 2) == 2) ? 256 : 0) + (w & 3) * 64; }

// Stage one [128][64] bf16 tile (16 KB), XOR-swizzled (chunk ^= row&7), async.
// 256 threads, 4 chunks each. LDS dst wave-uniform; per-lane global src.
__device__ inline void stage64(unsigned short* dstbase,
                               const unsigned short* __restrict__ src,
                               int srccol, int wave, int lane)
{
    #pragma unroll
    for (int s4 = 0; s4 < 4; ++s4) {
        const int c   = s4 * 256 + wave * 64 + lane;  // 0..1023
        const int r   = c >> 3;
        const int cin = (c & 7) ^ (r & 7);
        gld16(src + (size_t)r * KS + srccol + cin * 8,
              dstbase + (size_t)(s4 * 256 + wave * 64) * 8);
    }
}

// 4 fragments, rows rbase+{0,16,32,48}+lid, global chunk c0 (0..7), from a
// [*][64] XOR tile. Exact 2-way bank access = free.
__device__ inline void frag4_x64(const unsigned short (*T)[64], int rbase,
                                 int lid, int c0, short8 f[4])
{
    const int q = c0 ^ (lid & 7);
    #pragma unroll
    for (int i = 0; i < 4; ++i)
        f[i] = *(const short8*)&T[rbase + i * 16 + lid][q * 8];
}

// 4 fragments from a [*][32] XOR tile (BK=32 kernels: scores_self/xy).
__device__ inline void frag4_x32(const unsigned short (*T)[32], int rbase,
                                 int lid, int quad, short8 f[4])
{
    const int q = quad ^ (lid & 3);
    #pragma unroll
    for (int i = 0; i < 4; ++i)
        f[i] = *(const short8*)&T[rbase + i * 16 + lid][q * 8];
}

// Window -> col base, 32-slot windows (24) for scores_self.
__device__ inline int awin32(int w) { return (((w >> 3) == 1) ? 256 : 0) + (w & 7) * 32; }
__device__ inline int bwin32(int w) { return (((w >> 3) == 2) ? 256 : 0) + (w & 7) * 32; }

// ---------------------------------------------------------------------------
// Merged prep: convx (4608 blocks) | convw (96) | ylen (8). grid = 4712.
// ---------------------------------------------------------------------------
__global__ __launch_bounds__(256) void prep_kernel(
    const float* __restrict__ x, const float* __restrict__ y,
    const float* __restrict__ Wq, const float* __restrict__ Wk,
    const float* __restrict__ Wv, const int* __restrict__ mask_y,
    unsigned short* __restrict__ xs, unsigned short* __restrict__ Wb,
    float* __restrict__ ylen_out)
{
    const int bid = blockIdx.x;
    const int t   = threadIdx.x;
    if (bid < 4608) {                        // ---- convx: x|y -> planar xs
        const int g   = bid * 256 + t;       // < 1179648
        const int row = g >> 5;
        const int off = (g & 31) * 8;
        const float* src = (row < ROWS_X) ? (x + (size_t)row * DD)
                                          : (y + (size_t)(row - ROWS_X) * DD);
        float4 v0 = *(const float4*)(src + off);
        float4 v1 = *(const float4*)(src + off + 4);
        const float fv[8] = {v0.x, v0.y, v0.z, v0.w, v1.x, v1.y, v1.z, v1.w};
        short8 hh, ll;
        #pragma unroll
        for (int i = 0; i < 8; ++i) {
            unsigned short h = rne_bf16(fv[i]);
            hh[i] = (short)h;
            ll[i] = (short)rne_bf16(fv[i] - bf2f(h));
        }
        unsigned short* dst = xs + (size_t)row * KS;
        *(short8*)(dst + off)       = hh;
        *(short8*)(dst + 256 + off) = ll;
    } else if (bid < 4704) {                 // ---- convw: W -> planar Wb
        const int g  = (bid - 4608) * 256 + t;   // < 24576
        const int e  = g * 8;
        const int zi = e >> 16;
        const int off = e & 65535;
        const int row = off >> 8, k0 = off & 255;
        const float* W = (zi == 0) ? Wq : (zi == 1 ? Wk : Wv);
        float4 v0 = *(const float4*)(W + off);
        float4 v1 = *(const float4*)(W + off + 4);
        const float fv[8] = {v0.x, v0.y, v0.z, v0.w, v1.x, v1.y, v1.z, v1.w};
        short8 hh, ll;
        #pragma unroll
        for (int i = 0; i < 8; ++i) {
            unsigned short h = rne_bf16(fv[i]);
            hh[i] = (short)h;
            ll[i] = (short)rne_bf16(fv[i] - bf2f(h));
        }
        unsigned short* dst = Wb + (size_t)zi * 131072 + (size_t)row * KS;
        *(short8*)(dst + k0)       = hh;
        *(short8*)(dst + 256 + k0) = ll;
    } else {                                 // ---- ylen (wave 0 only)
        if (t < 64) {
            const int s = bid - 4704;
            int c = 0;
            #pragma unroll
            for (int k = 0; k < 8; ++k)
                c += (mask_y[s * MM + k * 64 + t] != 0);
            #pragma unroll
            for (int off = 32; off; off >>= 1) c += __shfl_xor(c, off);
            if (t < 8) ylen_out[t * 8 + s] = (float)c;
        }
    }
}

// ---------------------------------------------------------------------------
// Projections via MFMA, m97-style: BK=64, SERIAL 2-barrier staging (32 KB
// LDS -> 4 blocks/CU; implicit wave overlap hides staging; 32 MFMA per
// barrier drain). XCD-chunked: 6 consumers of each A-panel on one XCD.
// z=0 -> Qa, z=1 -> Kb (planar [h|l]); z=2 -> Vt[b][d][j]. grid = 1728.
// ---------------------------------------------------------------------------
__global__ __launch_bounds__(256) void proj_kernel(
    const unsigned short* __restrict__ xs,
    const unsigned short* __restrict__ Wb,
    unsigned short* __restrict__ Qa, unsigned short* __restrict__ Kb,
    unsigned short* __restrict__ Vt)
{
    // 1728 = 8 XCD * 216; per XCD: 36 consecutive bx, each with 6 (by,bz)
    const int xcd = blockIdx.x & 7, idx = blockIdx.x >> 3;
    const int lin = xcd * 216 + idx;
    const int bx  = lin / 6;
    const int rem = lin - bx * 6;
    const int z    = rem >> 1;
    const int row0 = bx * 128;
    const int col0 = (rem & 1) * 128;
    const unsigned short* Asrc = xs + (size_t)row0 * KS;
    const unsigned short* Bsrc = Wb + (size_t)z * 131072 + (size_t)col0 * KS;

    __shared__ unsigned short Ab[128][64];
    __shared__ unsigned short Bb[128][64];

    const int t = threadIdx.x;
    const int wave = t >> 6, lane = t & 63, quad = lane >> 4, lid = lane & 15;
    const int wrow = (wave & 1) * 64, wcol = (wave >> 1) * 64;

    f32x4 acc[4][4];
    #pragma unroll
    for (int i = 0; i < 4; ++i)
        #pragma unroll
        for (int j = 0; j < 4; ++j) acc[i][j] = (f32x4){0.f, 0.f, 0.f, 0.f};

    for (int w = 0; w < 12; ++w) {
        stage64(&Ab[0][0], Asrc, awin64(w), wave, lane);
        stage64(&Bb[0][0], Bsrc, bwin64(w), wave, lane);
        __syncthreads();
        #pragma unroll
        for (int kk = 0; kk < 64; kk += 32) {
            const int c0 = (kk >> 3) + quad;
            short8 af[4], bf_[4];
            frag4_x64(Ab, wrow, lid, c0, af);
            frag4_x64(Bb, wcol, lid, c0, bf_);
            #pragma unroll
            for (int i = 0; i < 4; ++i)
                #pragma unroll
                for (int j = 0; j < 4; ++j)
                    acc[i][j] = mfma16(af[i], bf_[j], acc[i][j]);
        }
        __syncthreads();
    }

    if (z == 2) {
        #pragma unroll
        for (int i = 0; i < 4; ++i) {
            const int rg = row0 + wrow + i * 16 + quad * 4;
            const int b  = rg >> 9;
            const int j  = rg & 511;
            #pragma unroll
            for (int jt = 0; jt < 4; ++jt) {
                const int col = col0 + wcol + jt * 16 + lid;
                *(ushort4*)(Vt + (size_t)b * DD * MM + (size_t)col * MM + j) =
                    make_ushort4(rne_bf16(acc[i][jt][0]), rne_bf16(acc[i][jt][1]),
                                 rne_bf16(acc[i][jt][2]), rne_bf16(acc[i][jt][3]));
            }
        }
    } else {
        unsigned short* dst = (z == 0) ? Qa : Kb;
        #pragma unroll
        for (int i = 0; i < 4; ++i) {
            const int rg = row0 + wrow + i * 16 + quad * 4;
            #pragma unroll
            for (int r = 0; r < 4; ++r) {
                unsigned short* rowp = dst + (size_t)(rg + r) * KS;
                #pragma unroll
                for (int jt = 0; jt < 4; ++jt) {
                    const int col = col0 + wcol + jt * 16 + lid;
                    const float v = acc[i][jt][r];
                    unsigned short h = rne_bf16(v);
                    rowp[col]       = h;                          // h-plane
                    rowp[256 + col] = rne_bf16(v - bf2f(h));      // l-plane
                }
            }
        }
    }
}

// ---------------------------------------------------------------------------
// FUSED self scores (x z<64, y z>=64): 64 rows x FULL 512 cols per block,
// k'=768 planar (24 x BK=32 windows, dbuf — LDS-bound at 72 KB, 2 blk/CU).
// Writes raw masked S (fp32), P = exp(S - m) (bf16, for ctx), inv = 1/sum.
// grid = 576 (8 XCD x 9 z x 8 row-blocks), 256 threads (4 col-waves).
// ---------------------------------------------------------------------------
__global__ __launch_bounds__(256, 2) void scores_self_kernel(
    const unsigned short* __restrict__ Qa,
    const unsigned short* __restrict__ Kb,
    const int* __restrict__ mask_x, const int* __restrict__ mask_y,
    float* __restrict__ Sbase, unsigned short* __restrict__ P,
    float* __restrict__ inv_all)
{
    const int xcd = blockIdx.x & 7, idx = blockIdx.x >> 3;
    const int lin = xcd * 72 + idx;          // 576 = 8*72
    const int z    = lin >> 3;               // 0..71
    const int brow = (lin & 7) * 64;
    const unsigned short* Asrc = Qa + (size_t)(z * MM + brow) * KS;
    const unsigned short* Bsrc = Kb + (size_t)z * MM * KS;
    const int* msk = (z < 64) ? (mask_x + z * MM) : (mask_y + (z - 64) * MM);
    float* S = Sbase + (size_t)z * MM * MM;

    __shared__ unsigned short Ab[2][64][32];
    __shared__ unsigned short Bb[2][512][32];
    __shared__ float pm4[64][4], ps4[64][4], smx[64];

    const int t = threadIdx.x;
    const int wave = t >> 6, lane = t & 63, quad = lane >> 4, lid = lane & 15;
    const int wcol = wave * 128;

    f32x4 acc[4][8];
    #pragma unroll
    for (int i = 0; i < 4; ++i)
        #pragma unroll
        for (int j = 0; j < 8; ++j) acc[i][j] = (f32x4){0.f, 0.f, 0.f, 0.f};

    auto stage = [&](int buf, int w) {
        {   // A: 64 rows x 4 chunks = 256 chunks, lane-ordered
            const int r = t >> 2, cin = (t & 3) ^ (r & 3);
            gld16(Asrc + (size_t)r * KS + awin32(w) + cin * 8,
                  &Ab[buf][0][0] + (size_t)(wave * 64) * 8);
        }
        const int bw = bwin32(w);
        #pragma unroll
        for (int k = 0; k < 8; ++k) {        // B: 512 rows x 4 chunks = 2048
            const int c = k * 256 + t;
            const int r = c >> 2, cin = (c & 3) ^ (r & 3);
            gld16(Bsrc + (size_t)r * KS + bw + cin * 8,
                  &Bb[buf][0][0] + (size_t)(k * 256 + wave * 64) * 8);
        }
    };
    auto comp = [&](int buf) {
        short8 af[4], bv[8];
        frag4_x32(Ab[buf], 0, lid, quad, af);
        frag4_x32(Bb[buf], wcol, lid, quad, bv);
        frag4_x32(Bb[buf], wcol + 64, lid, quad, bv + 4);
        #pragma unroll
        for (int i = 0; i < 4; ++i)
            #pragma unroll
            for (int j = 0; j < 8; ++j)
                acc[i][j] = mfma16(af[i], bv[j], acc[i][j]);
    };

    stage(0, 0);
    __syncthreads();
    int cur = 0;
    for (int w = 0; w < 23; ++w) {
        stage(cur ^ 1, w + 1);
        comp(cur);
        __syncthreads();
        cur ^= 1;
    }
    comp(cur);

    int mcol[8];
    #pragma unroll
    for (int j = 0; j < 8; ++j) mcol[j] = msk[wcol + j * 16 + lid];

    // pass 1: raw S writes + per-wave row partials
    #pragma unroll
    for (int i = 0; i < 4; ++i) {
        #pragma unroll
        for (int r = 0; r < 4; ++r) {
            const int rl = i * 16 + quad * 4 + r;
            const bool mr = (msk[brow + rl] != 0);
            float* Srow = S + (size_t)(brow + rl) * MM;
            float vv[8];
            float mt = -3.4e38f;
            #pragma unroll
            for (int j = 0; j < 8; ++j) {
                const int col = wcol + j * 16 + lid;
                const bool valid = mr && (mcol[j] != 0);
                vv[j] = valid ? acc[i][j][r] : NEG_FILL_F;
                Srow[col] = vv[j];
                mt = fmaxf(mt, vv[j]);
            }
            #pragma unroll
            for (int o = 1; o < 16; o <<= 1) mt = fmaxf(mt, __shfl_xor(mt, o));
            float se = 0.f;
            #pragma unroll
            for (int j = 0; j < 8; ++j) se += __expf(vv[j] - mt);
            #pragma unroll
            for (int o = 1; o < 16; o <<= 1) se += __shfl_xor(se, o);
            if (lid == 0) { pm4[rl][wave] = mt; ps4[rl][wave] = se; }
        }
    }
    __syncthreads();
    if (t < 64) {
        const float m = fmaxf(fmaxf(pm4[t][0], pm4[t][1]),
                              fmaxf(pm4[t][2], pm4[t][3]));
        float s = 0.f;
        #pragma unroll
        for (int c = 0; c < 4; ++c) s += ps4[t][c] * __expf(pm4[t][c] - m);
        smx[t] = m;
        inv_all[z * MM + brow + t] = 1.0f / s;   // all-masked: m=NEG, s=512
    }
    __syncthreads();
    // pass 2: P = exp(S - m) bf16 (exact values ctx's exp stage produced)
    #pragma unroll
    for (int i = 0; i < 4; ++i) {
        #pragma unroll
        for (int r = 0; r < 4; ++r) {
            const int rl = i * 16 + quad * 4 + r;
            const bool mr = (msk[brow + rl] != 0);
            const float m = smx[rl];
            unsigned short* Prow = P + (size_t)(z * MM + brow + rl) * KS;
            #pragma unroll
            for (int j = 0; j < 8; ++j) {
                const int col = wcol + j * 16 + lid;
                const bool valid = mr && (mcol[j] != 0);
                const float v = valid ? acc[i][j][r] : NEG_FILL_F;
                Prow[col] = rne_bf16(__expf(v - m));
            }
        }
    }
}

// ---------------------------------------------------------------------------
// FUSED cross scores (xy): 64 rows x full 512 cols, single bf16 K=256
// (h-plane), 8 x BK=32 windows dbuf. Writes FINAL probs + mask floats.
// grid = 512 (8 XCD x 8 zz s-major x 8 rb).
// ---------------------------------------------------------------------------
__global__ __launch_bounds__(256, 2) void scores_xy_kernel(
    const unsigned short* __restrict__ Qa, const unsigned short* __restrict__ Kb,
    const int* __restrict__ mask_x, const int* __restrict__ mask_y,
    float* __restrict__ Prb, float* __restrict__ Mb)
{
    const int xcd = blockIdx.x & 7, idx = blockIdx.x >> 3;
    const int lin = xcd * 64 + idx;          // 512 = 8*64
    const int zz = lin >> 3;                 // s-major
    const int brow = (lin & 7) * 64;
    const int s = zz >> 3, n = zz & 7;
    const int zo = n * 8 + s;                // output slot (reference order)
    const int bq = s * 8 + n;                // x batch
    const int bk = s;                        // y batch
    const unsigned short* Asrc = Qa + (size_t)(bq * MM + brow) * KS;
    const unsigned short* Bsrc = Kb + (size_t)(ROWS_X + bk * MM) * KS;
    const int* mq = mask_x + bq * MM;
    const int* mk = mask_y + bk * MM;
    float* Pl = Prb + (size_t)zo * MM * MM;
    float* Ml = Mb  + (size_t)zo * MM * MM;

    __shared__ unsigned short Ab[2][64][32];
    __shared__ unsigned short Bb[2][512][32];
    __shared__ float pm4[64][4], ps4[64][4], smx[64], sin_[64];

    const int t = threadIdx.x;
    const int wave = t >> 6, lane = t & 63, quad = lane >> 4, lid = lane & 15;
    const int wcol = wave * 128;

    f32x4 acc[4][8];
    #pragma unroll
    for (int i = 0; i < 4; ++i)
        #pragma unroll
        for (int j = 0; j < 8; ++j) acc[i][j] = (f32x4){0.f, 0.f, 0.f, 0.f};

    auto stage = [&](int buf, int w) {
        {
            const int r = t >> 2, cin = (t & 3) ^ (r & 3);
            gld16(Asrc + (size_t)r * KS + w * 32 + cin * 8,
                  &Ab[buf][0][0] + (size_t)(wave * 64) * 8);
        }
        #pragma unroll
        for (int k = 0; k < 8; ++k) {
            const int c = k * 256 + t;
            const int r = c >> 2, cin = (c & 3) ^ (r & 3);
            gld16(Bsrc + (size_t)r * KS + w * 32 + cin * 8,
                  &Bb[buf][0][0] + (size_t)(k * 256 + wave * 64) * 8);
        }
    };
    auto comp = [&](int buf) {
        short8 af[4], bv[8];
        frag4_x32(Ab[buf], 0, lid, quad, af);
        frag4_x32(Bb[buf], wcol, lid, quad, bv);
        frag4_x32(Bb[buf], wcol + 64, lid, quad, bv + 4);
        #pragma unroll
        for (int i = 0; i < 4; ++i)
            #pragma unroll
            for (int j = 0; j < 8; ++j)
                acc[i][j] = mfma16(af[i], bv[j], acc[i][j]);
    };

    stage(0, 0);
    __syncthreads();
    int cur = 0;
    for (int w = 0; w < 7; ++w) {
        stage(cur ^ 1, w + 1);
        comp(cur);
        __syncthreads();
        cur ^= 1;
    }
    comp(cur);

    int mcol[8];
    #pragma unroll
    for (int j = 0; j < 8; ++j) mcol[j] = mk[wcol + j * 16 + lid];

    // pass 1: mask floats + partials
    #pragma unroll
    for (int i = 0; i < 4; ++i) {
        #pragma unroll
        for (int r = 0; r < 4; ++r) {
            const int rl = i * 16 + quad * 4 + r;
            const bool mr = (mq[brow + rl] != 0);
            float* Mrow = Ml + (size_t)(brow + rl) * MM;
            float vv[8];
            float mt = -3.4e38f;
            #pragma unroll
            for (int j = 0; j < 8; ++j) {
                const int col = wcol + j * 16 + lid;
                const bool valid = mr && (mcol[j] != 0);
                vv[j] = valid ? acc[i][j][r] : NEG_FILL_F;
                Mrow[col] = valid ? 1.0f : 0.0f;
                mt = fmaxf(mt, vv[j]);
            }
            #pragma unroll
            for (int o = 1; o < 16; o <<= 1) mt = fmaxf(mt, __shfl_xor(mt, o));
            float se = 0.f;
            #pragma unroll
            for (int j = 0; j < 8; ++j) se += __expf(vv[j] - mt);
            #pragma unroll
            for (int o = 1; o < 16; o <<= 1) se += __shfl_xor(se, o);
            if (lid == 0) { pm4[rl][wave] = mt; ps4[rl][wave] = se; }
        }
    }
    __syncthreads();
    if (t < 64) {
        const float m = fmaxf(fmaxf(pm4[t][0], pm4[t][1]),
                              fmaxf(pm4[t][2], pm4[t][3]));
        float ssum = 0.f;
        #pragma unroll
        for (int c = 0; c < 4; ++c) ssum += ps4[t][c] * __expf(pm4[t][c] - m);
        smx[t] = m;
        sin_[t] = 1.0f / ssum;
    }
    __syncthreads();
    // pass 2: final probs (no raw-S write, no second kernel)
    #pragma unroll
    for (int i = 0; i < 4; ++i) {
        #pragma unroll
        for (int r = 0; r < 4; ++r) {
            const int rl = i * 16 + quad * 4 + r;
            const bool mr = (mq[brow + rl] != 0);
            const float m = smx[rl], iv = sin_[rl];
            float* Prow = Pl + (size_t)(brow + rl) * MM;
            #pragma unroll
            for (int j = 0; j < 8; ++j) {
                const int col = wcol + j * 16 + lid;
                const bool valid = mr && (mcol[j] != 0);
                const float v = valid ? acc[i][j][r] : NEG_FILL_F;
                Prow[col] = __expf(v - m) * iv;
            }
        }
    }
}

// ---------------------------------------------------------------------------
// Context: pure async-staged GEMM, m97-style BK=64 SERIAL (8 windows, 40 KB
// LDS -> 4 blocks/CU). A = P (bf16 exp-probs, stride KS); B = Vt.
// 64 rows x 256 cols per block, epilogue scales by inv.
// grid = 576 (8 XCD x 9 b x 8 rb), 256 thr.
// ---------------------------------------------------------------------------
__global__ __launch_bounds__(256) void ctx_kernel(
    const unsigned short* __restrict__ P, const float* __restrict__ inv_all,
    const unsigned short* __restrict__ Vt_base, float* __restrict__ Obase)
{
    const int xcd = blockIdx.x & 7, idx = blockIdx.x >> 3;
    const int lin = xcd * 72 + idx;          // 576 = 8*72
    const int b    = lin >> 3;
    const int brow = (lin & 7) * 64;
    const unsigned short* Psrc = P + (size_t)(b * MM + brow) * KS;
    const unsigned short* Vt   = Vt_base + (size_t)b * DD * MM;
    float*                O    = Obase + (size_t)b * MM * DD;
    const float*          iv   = inv_all + b * MM + brow;

    __shared__ unsigned short Ab[64][64];    // 8 KB
    __shared__ unsigned short Bb[256][64];   // 32 KB

    const int t = threadIdx.x;
    const int wave = t >> 6, lane = t & 63, quad = lane >> 4, lid = lane & 15;
    const int wcol = wave * 64;

    f32x4 acc[4][4];
    #pragma unroll
    for (int i = 0; i < 4; ++i)
        #pragma unroll
        for (int j = 0; j < 4; ++j) acc[i][j] = (f32x4){0.f, 0.f, 0.f, 0.f};

    for (int w = 0; w < 8; ++w) {
        // A: 64 rows x 8 chunks = 512 chunks, 2 per thread
        #pragma unroll
        for (int s4 = 0; s4 < 2; ++s4) {
            const int c = s4 * 256 + wave * 64 + lane;   // 0..511
            const int r = c >> 3, cin = (c & 7) ^ (r & 7);
            gld16(Psrc + (size_t)r * KS + w * 64 + cin * 8,
                  &Ab[0][0] + (size_t)(s4 * 256 + wave * 64) * 8);
        }
        // B: 256 rows (d) x 8 chunks = 2048 chunks, 8 per thread
        #pragma unroll
        for (int k = 0; k < 8; ++k) {
            const int c = k * 256 + wave * 64 + lane;
            const int r = c >> 3, cin = (c & 7) ^ (r & 7);
            gld16(Vt + (size_t)r * MM + w * 64 + cin * 8,
                  &Bb[0][0] + (size_t)(k * 256 + wave * 64) * 8);
        }
        __syncthreads();
        #pragma unroll
        for (int kk = 0; kk < 64; kk += 32) {
            const int c0 = (kk >> 3) + quad;
            short8 af[4], bf_[4];
            frag4_x64(Ab, 0, lid, c0, af);
            frag4_x64(Bb, wcol, lid, c0, bf_);
            #pragma unroll
            for (int i = 0; i < 4; ++i)
                #pragma unroll
                for (int j = 0; j < 4; ++j)
                    acc[i][j] = mfma16(af[i], bf_[j], acc[i][j]);
        }
        __syncthreads();
    }

    #pragma unroll
    for (int i = 0; i < 4; ++i) {
        const int rl0 = i * 16 + quad * 4;
        float inv[4];
        #pragma unroll
        for (int r = 0; r < 4; ++r) inv[r] = iv[rl0 + r];
        #pragma unroll
        for (int jt = 0; jt < 4; ++jt) {
            const int col = wcol + jt * 16 + lid;
            #pragma unroll
            for (int r = 0; r < 4; ++r)
                O[(size_t)(brow + rl0 + r) * DD + col] = acc[i][jt][r] * inv[r];
        }
    }
}

// ---------------------------------------------------------------------------
extern "C" void kernel_launch(void* const* d_in, const int* in_sizes, int n_in,
                              void* d_out, int out_size, void* d_ws, size_t ws_size,
                              hipStream_t stream)
{
    const float* x      = (const float*)d_in[0];
    const float* y      = (const float*)d_in[1];
    const int*   mask_x = (const int*)d_in[2];
    const int*   mask_y = (const int*)d_in[3];
    const float* Wq     = (const float*)d_in[4];
    const float* Wk     = (const float*)d_in[5];
    const float* Wv     = (const float*)d_in[6];
    float* out = (float*)d_out;

    // Workspace: Wb | xs | Qa | Kb | Vt | inv
    unsigned short* Wb = (unsigned short*)d_ws;            // 3*256*512   = 393216
    unsigned short* xs = Wb + 393216;                      // 36864*512   = 18874368
    unsigned short* Qa = xs + 18874368;
    unsigned short* Kb = Qa + 18874368;
    unsigned short* Vt = Kb + 18874368;                    // 72*256*512  = 9437184
    float* inv_all = (float*)(Vt + 9437184);               // 36864 floats

    // Output slots (floats, concatenated in reference return order)
    float* out_ctx   = out;                 // 64*512*256 + 8*512*256
    float* out_sx    = out + 9437184;       // 64*512*512 (+sy)
    float* out_pxy   = out + 28311552;      // 8*8*512*512
    float* out_mxy   = out + 45088768;      // 8*8*512*512
    float* out_ylen  = out + 61865984;      // 8*8

    // P (bf16 [36864][512], 37.7MB) lives in out_pxy scratch: produced by
    // scores_self, consumed by ctx, then pxy overwritten by scores_xy.
    unsigned short* P = (unsigned short*)out_pxy;

    // 1. merged prep: convx | convw | ylen
    prep_kernel<<<4712, 256, 0, stream>>>(x, y, Wq, Wk, Wv, mask_y,
                                          xs, Wb, out_ylen);

    // 2. Projections (BK=64 serial, XCD-chunked)
    proj_kernel<<<1728, 256, 0, stream>>>(xs, Wb, Qa, Kb, Vt);

    // 3. Self scores (fused softmax stats -> S, P, inv)
    scores_self_kernel<<<576, 256, 0, stream>>>(
        Qa, Kb, mask_x, mask_y, out_sx, P, inv_all);

    // 4. Context (BK=64 serial; reads P before xy overwrites the region)
    ctx_kernel<<<576, 256, 0, stream>>>(P, inv_all, Vt, out_ctx);

    // 5. Cross scores (fused softmax -> final probs + mask)
    scores_xy_kernel<<<512, 256, 0, stream>>>(
        Qa, Kb, mask_x, mask_y, out_pxy, out_mxy);
}